// Round 8
// baseline (386.745 us; speedup 1.0000x reference)
//
#include <hip/hip_runtime.h>
#include <hip/hip_bf16.h>

// Transformer-XL relative MHA. fp32 in/out, bf16 intermediates in d_ws.
// B=8 T=1024 D_MODEL=512 H=8 DH=64.
// R8: attn reads K/V/P MFMA fragments DIRECTLY from global (L2-resident,
// 64B-segment coalesced); LDS keeps only per-wave Gl + Prob -> the chunk
// loop is barrier-free and LDS drops to 29.7KB (4-5 blocks/CU).
// R7's shuffle-Prob regressed (bpermute = LDS pipe) -> reverted to R6 Prob.
// Rel-shift identity: bd[t,s] = q_v[t] . p[1023 - t + s].

typedef unsigned short u16;
typedef unsigned long long u64;
typedef __attribute__((ext_vector_type(8))) short bf16x8;
typedef __attribute__((ext_vector_type(8))) unsigned short ushort8v;
typedef __attribute__((ext_vector_type(4))) float floatx4;

__device__ __forceinline__ float b2f(u16 u) {
    union { unsigned int i; float f; } x; x.i = ((unsigned int)u) << 16; return x.f;
}
__device__ __forceinline__ u16 f2b(float f) {
    __hip_bfloat16 h = __float2bfloat16(f);
    return *reinterpret_cast<u16*>(&h);
}

#define MFMA16(a, b, c) __builtin_amdgcn_mfma_f32_16x16x32_bf16(a, b, c, 0, 0, 0)

// ---------------------------------------------------------------- prep
// blocks [0,2048): castX ; [2048,2304): castW (4 matrices) ; [2304,4352): maskpack
__global__ __launch_bounds__(256) void prep_kernel(
    const float* __restrict__ X, u16* __restrict__ Xb,
    const float* __restrict__ W0, const float* __restrict__ W1,
    const float* __restrict__ W2, const float* __restrict__ W3,
    u16* __restrict__ WT,
    const int* __restrict__ mask, u64* __restrict__ Mp)
{
    const int bi = blockIdx.x;
    const int tid = threadIdx.x;
    if (bi < 2048) {
        size_t i = ((size_t)bi * 256 + tid) * 8;
        float4 a = *(const float4*)&X[i];
        float4 b = *(const float4*)&X[i + 4];
        ushort8v s;
        s[0] = f2b(a.x); s[1] = f2b(a.y); s[2] = f2b(a.z); s[3] = f2b(a.w);
        s[4] = f2b(b.x); s[5] = f2b(b.y); s[6] = f2b(b.z); s[7] = f2b(b.w);
        *(ushort8v*)&Xb[i] = s;
    } else if (bi < 2304) {
        __shared__ float t[64][68];
        const int li = bi - 2048;
        const int m = li >> 6;
        const float* src = (m == 0) ? W0 : (m == 1) ? W1 : (m == 2) ? W2 : W3;
        u16* dst = WT + (size_t)m * 262144;
        const int k0 = ((li >> 3) & 7) * 64, n0 = (li & 7) * 64;
        const int r = tid >> 4, c = tid & 15;
#pragma unroll
        for (int rr = 0; rr < 64; rr += 16) {
            float4 v = *(const float4*)&src[(size_t)(k0 + r + rr) * 512 + n0 + 4 * c];
            t[r + rr][4 * c + 0] = v.x;
            t[r + rr][4 * c + 1] = v.y;
            t[r + rr][4 * c + 2] = v.z;
            t[r + rr][4 * c + 3] = v.w;
        }
        __syncthreads();
        const int nrow = tid >> 2, kc = (tid & 3) * 16;
        ushort8v s0, s1;
#pragma unroll
        for (int e = 0; e < 8; ++e) {
            s0[e] = f2b(t[kc + e][nrow]);
            s1[e] = f2b(t[kc + 8 + e][nrow]);
        }
        *(ushort8v*)&dst[(size_t)(n0 + nrow) * 512 + k0 + kc] = s0;
        *(ushort8v*)&dst[(size_t)(n0 + nrow) * 512 + k0 + kc + 8] = s1;
    } else {
        const int lane = tid & 63, w = tid >> 6;
        const int row = (bi - 2304) * 4 + w;
#pragma unroll
        for (int j = 0; j < 16; ++j) {
            int v = mask[(size_t)row * 1024 + j * 64 + lane];
            u64 bits = __ballot(v != 0);
            if (lane == j) Mp[(size_t)row * 16 + j] = bits;
        }
    }
}

// ---------------------------------------------------------------- pos kernel
__global__ __launch_bounds__(256) void pos_kernel(const float* __restrict__ Wpos,
                                                  u16* __restrict__ P) {
    __shared__ float pe[8][512];
    const int tid = threadIdx.x;
    const int l0 = blockIdx.x * 8;
    float invf = expf(-9.210340371976184f * ((float)tid / 256.0f));
    for (int il = 0; il < 8; ++il) {
        int l = l0 + il; if (l > 2046) l = 2046;
        float ang = (float)(l - 1023) * invf;
        pe[il][2 * tid]     = sinf(ang);
        pe[il][2 * tid + 1] = cosf(ang);
    }
    __syncthreads();
    float acc[8][2];
    for (int il = 0; il < 8; ++il) { acc[il][0] = 0.f; acc[il][1] = 0.f; }
    for (int k = 0; k < 512; ++k) {
        float w0 = Wpos[k * 512 + tid];
        float w1 = Wpos[k * 512 + tid + 256];
#pragma unroll
        for (int il = 0; il < 8; ++il) {
            float pk = pe[il][k];
            acc[il][0] = fmaf(pk, w0, acc[il][0]);
            acc[il][1] = fmaf(pk, w1, acc[il][1]);
        }
    }
    for (int il = 0; il < 8; ++il) {
        int l = l0 + il; if (l >= 2047) break;
        int c0 = tid, c1 = tid + 256;
        P[((size_t)(c0 >> 6) * 2047 + l) * 64 + (c0 & 63)] = f2b(acc[il][0]);
        P[((size_t)(c1 >> 6) * 2047 + l) * 64 + (c1 & 63)] = f2b(acc[il][1]);
    }
}

// ---------------------------------------------------------------- qkv MFMA
// grid (64, 12): x -> 128 rows of xs; y: 0-3 Q, 4-7 K, 8-11 V (n0=(y&3)*128).
// Prefetch pipeline: load k-chunk i+1 into regs during compute of chunk i.
__global__ __launch_bounds__(256, 2) void qkv_mfma(
    const u16* __restrict__ Xb, const u16* __restrict__ WqT,
    const u16* __restrict__ WkT, const u16* __restrict__ WvT,
    u16* __restrict__ Qb, u16* __restrict__ Kb, u16* __restrict__ Vtg)
{
    __shared__ u16 Xl[128 * 40];
    __shared__ u16 Wl[128 * 40];
    const int tid = threadIdx.x;
    const int lane = tid & 63, w = tid >> 6;
    const int quad = lane >> 4, ln = lane & 15;
    const int wm = w & 1, wn = w >> 1;

    const int m0 = blockIdx.x * 128;
    const int sel = blockIdx.y >> 2;
    const int n0 = (blockIdx.y & 3) * 128;
    const u16* WT = (sel == 0) ? WqT : (sel == 1) ? WkT : WvT;
    const int b = m0 >> 10, tbase = m0 & 1023;

    const int sr = tid >> 2, sg = tid & 3;

    floatx4 acc[4][4];
#pragma unroll
    for (int i = 0; i < 4; ++i)
#pragma unroll
        for (int j = 0; j < 4; ++j) acc[i][j] = (floatx4){0.f, 0.f, 0.f, 0.f};

    ushort8v xq[2], wq2[2];
#pragma unroll
    for (int it = 0; it < 2; ++it) {
        int r = sr + it * 64;
        xq[it]  = *(const ushort8v*)&Xb[(size_t)(m0 + r) * 512 + sg * 8];
        wq2[it] = *(const ushort8v*)&WT[(size_t)(n0 + r) * 512 + sg * 8];
    }

    for (int kc = 0; kc < 512; kc += 32) {
        __syncthreads();
#pragma unroll
        for (int it = 0; it < 2; ++it) {
            int r = sr + it * 64;
            *(ushort8v*)&Xl[r * 40 + sg * 8] = xq[it];
            *(ushort8v*)&Wl[r * 40 + sg * 8] = wq2[it];
        }
        __syncthreads();
        if (kc + 32 < 512) {
#pragma unroll
            for (int it = 0; it < 2; ++it) {
                int r = sr + it * 64;
                xq[it]  = *(const ushort8v*)&Xb[(size_t)(m0 + r) * 512 + kc + 32 + sg * 8];
                wq2[it] = *(const ushort8v*)&WT[(size_t)(n0 + r) * 512 + kc + 32 + sg * 8];
            }
        }
        bf16x8 am[4], an[4];
#pragma unroll
        for (int i = 0; i < 4; ++i)
            am[i] = *(bf16x8*)&Xl[(wm * 64 + i * 16 + ln) * 40 + quad * 8];
#pragma unroll
        for (int j = 0; j < 4; ++j)
            an[j] = *(bf16x8*)&Wl[(wn * 64 + j * 16 + ln) * 40 + quad * 8];
        if (sel < 2) {
#pragma unroll
            for (int i = 0; i < 4; ++i)
#pragma unroll
                for (int j = 0; j < 4; ++j)
                    acc[i][j] = MFMA16(an[j], am[i], acc[i][j]);
        } else {
#pragma unroll
            for (int i = 0; i < 4; ++i)
#pragma unroll
                for (int j = 0; j < 4; ++j)
                    acc[i][j] = MFMA16(am[i], an[j], acc[i][j]);
        }
    }
    if (sel < 2) {
        u16* dst = (sel == 0) ? Qb : Kb;
#pragma unroll
        for (int i = 0; i < 4; ++i) {
            int t = tbase + wm * 64 + i * 16 + ln;
#pragma unroll
            for (int j = 0; j < 4; ++j) {
                int n = n0 + wn * 64 + j * 16 + quad * 4;
                int h = n >> 6, d = n & 63;
                ushort4 s;
                s.x = f2b(acc[i][j][0]); s.y = f2b(acc[i][j][1]);
                s.z = f2b(acc[i][j][2]); s.w = f2b(acc[i][j][3]);
                *(ushort4*)&dst[(((size_t)b * 8 + h) * 1024 + t) * 64 + d] = s;
            }
        }
    } else {
#pragma unroll
        for (int i = 0; i < 4; ++i) {
            int t4 = tbase + wm * 64 + i * 16 + quad * 4;
#pragma unroll
            for (int j = 0; j < 4; ++j) {
                int n = n0 + wn * 64 + j * 16 + ln;
                int h = n >> 6, d = n & 63;
                ushort4 s;
                s.x = f2b(acc[i][j][0]); s.y = f2b(acc[i][j][1]);
                s.z = f2b(acc[i][j][2]); s.w = f2b(acc[i][j][3]);
                *(ushort4*)&Vtg[(((size_t)b * 8 + h) * 64 + d) * 1024 + t4] = s;
            }
        }
    }
}

// ---------------------------------------------------------------- attention
__device__ __forceinline__ bf16x8 addbias(bf16x8 q, const float* __restrict__ bias) {
    float4 a = *(const float4*)&bias[0];
    float4 b = *(const float4*)&bias[4];
    bf16x8 r;
    r[0] = (short)f2b(b2f((u16)q[0]) + a.x);
    r[1] = (short)f2b(b2f((u16)q[1]) + a.y);
    r[2] = (short)f2b(b2f((u16)q[2]) + a.z);
    r[3] = (short)f2b(b2f((u16)q[3]) + a.w);
    r[4] = (short)f2b(b2f((u16)q[4]) + b.x);
    r[5] = (short)f2b(b2f((u16)q[5]) + b.y);
    r[6] = (short)f2b(b2f((u16)q[6]) + b.z);
    r[7] = (short)f2b(b2f((u16)q[7]) + b.w);
    return r;
}

// Block = (b, h, 64 q-rows) = 4 waves x 16 rows. S-chunks of 64.
// K/V/P fragments loaded directly from global: per-lane addr = row(ln)*stride
// + quad*16B; equal-ln lanes across quads form 64B segments (coalesced).
// L2-resident via XCD swizzle (bid&7 owns 8 (b,h) pairs, 2MB < 4MB L2/XCD).
// LDS only holds per-wave Gl + Prob -> NO barriers in the chunk loop.
// P row index can reach 2047 only for the unused j=79 window row; the P
// buffer has >=64 rows of pad, and garbage there never reaches the output.
__global__ __launch_bounds__(256, 4) void attn_mfma(
    const u16* __restrict__ Qb,
    const u16* __restrict__ Kb, const u16* __restrict__ Vtg,
    const u16* __restrict__ P, const u64* __restrict__ Mp,
    const float* __restrict__ ub, const float* __restrict__ vb,
    u16* __restrict__ Z)
{
    __shared__ float Gl[4][16 * 80];       // per wave: [tt][j] stride 80
    __shared__ u16 Prob[4][16 * 72];       // per wave: [tt][ss] stride 72

    const int tid  = threadIdx.x;
    const int lane = tid & 63;
    const int w    = tid >> 6;
    const int quad = lane >> 4;
    const int ln   = lane & 15;

    const int bid = blockIdx.x;
    const int xg  = bid & 7;
    const int idx = bid >> 3;
    const int bh_i = xg * 8 + (idx >> 4);
    const int t0 = (idx & 15) << 6;
    const int h  = bh_i & 7;
    const int b  = bh_i >> 3;
    const size_t bh  = (size_t)bh_i * 1024;
    const size_t bhd = (size_t)bh_i * 64;
    const size_t mprow = ((size_t)b * 1024 + t0 + 16 * w + ln) * 16;

    // register B-fragments with bias add (once per block)
    const size_t qoff = (bh + t0 + 16 * w + ln) * 64;
    const bf16x8 q0 = *(const bf16x8*)&Qb[qoff + quad * 8];
    const bf16x8 q1 = *(const bf16x8*)&Qb[qoff + 32 + quad * 8];
    const bf16x8 qu0 = addbias(q0, &ub[h * 64 + quad * 8]);
    const bf16x8 qu1 = addbias(q1, &ub[h * 64 + 32 + quad * 8]);
    const bf16x8 qv0 = addbias(q0, &vb[h * 64 + quad * 8]);
    const bf16x8 qv1 = addbias(q1, &vb[h * 64 + 32 + quad * 8]);

    floatx4 O0 = {0.f, 0.f, 0.f, 0.f}, O1 = O0, O2 = O0, O3 = O0;
    float m_run = -3.0e38f, l_run = 0.f;

    float* gw = &Gl[w][0];
    u16* pw = &Prob[w][0];

    for (int s0 = 0; s0 < 1024; s0 += 64) {
        const u64 bits = Mp[mprow + (s0 >> 6)];
        const int lb0 = 960 - t0 + s0 + 48 - 16 * w;

        // BD: G^T[j][tt] = Pband . Qv^T  (A-frags direct from P)
#pragma unroll
        for (int jt = 0; jt < 5; ++jt) {
            const u16* pr = &P[((size_t)h * 2047 + lb0 + jt * 16 + ln) * 64];
            bf16x8 a0 = *(const bf16x8*)&pr[quad * 8];
            bf16x8 a1 = *(const bf16x8*)&pr[32 + quad * 8];
            floatx4 g = {0.f, 0.f, 0.f, 0.f};
            g = MFMA16(a0, qv0, g);
            g = MFMA16(a1, qv1, g);
            *(floatx4*)&gw[ln * 80 + jt * 16 + quad * 4] = g;
        }
        // AC: S^T[ss][tt] = K . Qu^T  (A-frags direct from Kb)
        floatx4 cac[4];
#pragma unroll
        for (int st = 0; st < 4; ++st) {
            const u16* kr = &Kb[(bh + s0 + st * 16 + ln) * 64];
            bf16x8 a0 = *(const bf16x8*)&kr[quad * 8];
            bf16x8 a1 = *(const bf16x8*)&kr[32 + quad * 8];
            floatx4 c = {0.f, 0.f, 0.f, 0.f};
            c = MFMA16(a0, qu0, c);
            c = MFMA16(a1, qu1, c);
            cac[st] = c;
        }
        // scores + online softmax (lane owns col tt = ln)
        float sc[4][4];
        float cmax = -3.0e38f;
#pragma unroll
        for (int st = 0; st < 4; ++st) {
            int j0 = st * 16 + quad * 4 + 15 - ln;
#pragma unroll
            for (int r = 0; r < 4; ++r) {
                float v = (cac[st][r] + gw[ln * 80 + j0 + r]) * 0.125f;
                int ss = st * 16 + quad * 4 + r;
                v = ((bits >> ss) & 1ull) ? v : -1.0e30f;
                sc[st][r] = v;
                cmax = fmaxf(cmax, v);
            }
        }
        cmax = fmaxf(cmax, __shfl_xor(cmax, 16));
        cmax = fmaxf(cmax, __shfl_xor(cmax, 32));
        float m_new = fmaxf(m_run, cmax);
        float alpha = __expf(m_run - m_new);
        float psum = 0.f;
#pragma unroll
        for (int st = 0; st < 4; ++st) {
            float p0 = __expf(sc[st][0] - m_new);
            float p1 = __expf(sc[st][1] - m_new);
            float p2 = __expf(sc[st][2] - m_new);
            float p3 = __expf(sc[st][3] - m_new);
            psum += (p0 + p1) + (p2 + p3);
            ushort4 pk;
            pk.x = f2b(p0); pk.y = f2b(p1); pk.z = f2b(p2); pk.w = f2b(p3);
            *(ushort4*)&pw[ln * 72 + st * 16 + quad * 4] = pk;
        }
        psum += __shfl_xor(psum, 16);
        psum += __shfl_xor(psum, 32);
        l_run = l_run * alpha + psum;
        m_run = m_new;
        float a0s = __shfl(alpha, quad * 4 + 0);
        float a1s = __shfl(alpha, quad * 4 + 1);
        float a2s = __shfl(alpha, quad * 4 + 2);
        float a3s = __shfl(alpha, quad * 4 + 3);
        O0[0] *= a0s; O0[1] *= a1s; O0[2] *= a2s; O0[3] *= a3s;
        O1[0] *= a0s; O1[1] *= a1s; O1[2] *= a2s; O1[3] *= a3s;
        O2[0] *= a0s; O2[1] *= a1s; O2[2] *= a2s; O2[3] *= a3s;
        O3[0] *= a0s; O3[1] *= a1s; O3[2] *= a2s; O3[3] *= a3s;
        // PV: O[t][d] += Prob . V  (A from Prob LDS, B direct from Vtg)
        bf16x8 pa0 = *(bf16x8*)&pw[ln * 72 + quad * 8];
        bf16x8 pa1 = *(bf16x8*)&pw[ln * 72 + 32 + quad * 8];
        {
            const u16* vr = &Vtg[(bhd + 0 + ln) * 1024 + s0];
            bf16x8 v0 = *(const bf16x8*)&vr[quad * 8];
            bf16x8 v1 = *(const bf16x8*)&vr[32 + quad * 8];
            O0 = MFMA16(pa0, v0, O0); O0 = MFMA16(pa1, v1, O0);
        }
        {
            const u16* vr = &Vtg[(bhd + 16 + ln) * 1024 + s0];
            bf16x8 v0 = *(const bf16x8*)&vr[quad * 8];
            bf16x8 v1 = *(const bf16x8*)&vr[32 + quad * 8];
            O1 = MFMA16(pa0, v0, O1); O1 = MFMA16(pa1, v1, O1);
        }
        {
            const u16* vr = &Vtg[(bhd + 32 + ln) * 1024 + s0];
            bf16x8 v0 = *(const bf16x8*)&vr[quad * 8];
            bf16x8 v1 = *(const bf16x8*)&vr[32 + quad * 8];
            O2 = MFMA16(pa0, v0, O2); O2 = MFMA16(pa1, v1, O2);
        }
        {
            const u16* vr = &Vtg[(bhd + 48 + ln) * 1024 + s0];
            bf16x8 v0 = *(const bf16x8*)&vr[quad * 8];
            bf16x8 v1 = *(const bf16x8*)&vr[32 + quad * 8];
            O3 = MFMA16(pa0, v0, O3); O3 = MFMA16(pa1, v1, O3);
        }
    }
    float li0 = 1.0f / __shfl(l_run, quad * 4 + 0);
    float li1 = 1.0f / __shfl(l_run, quad * 4 + 1);
    float li2 = 1.0f / __shfl(l_run, quad * 4 + 2);
    float li3 = 1.0f / __shfl(l_run, quad * 4 + 3);
    float li[4] = {li0, li1, li2, li3};
#pragma unroll
    for (int r = 0; r < 4; ++r) {
        size_t zo = ((size_t)b * 1024 + t0 + 16 * w + quad * 4 + r) * 512 + h * 64 + ln;
        Z[zo + 0]  = f2b(O0[r] * li[r]);
        Z[zo + 16] = f2b(O1[r] * li[r]);
        Z[zo + 32] = f2b(O2[r] * li[r]);
        Z[zo + 48] = f2b(O3[r] * li[r]);
    }
}

// ---------------------------------------------------------------- out MFMA
__global__ __launch_bounds__(256, 2) void out_mfma(
    const u16* __restrict__ Zb, const u16* __restrict__ WoT,
    float* __restrict__ out)
{
    __shared__ u16 Xl[128 * 40];
    __shared__ u16 Wl[128 * 40];
    const int tid = threadIdx.x;
    const int lane = tid & 63, w = tid >> 6;
    const int quad = lane >> 4, ln = lane & 15;
    const int wm = w & 1, wn = w >> 1;
    const int m0 = blockIdx.x * 128;
    const int n0 = blockIdx.y * 128;
    const int sr = tid >> 2, sg = tid & 3;

    floatx4 acc[4][4];
#pragma unroll
    for (int i = 0; i < 4; ++i)
#pragma unroll
        for (int j = 0; j < 4; ++j) acc[i][j] = (floatx4){0.f, 0.f, 0.f, 0.f};

    ushort8v xq[2], wq2[2];
#pragma unroll
    for (int it = 0; it < 2; ++it) {
        int r = sr + it * 64;
        xq[it]  = *(const ushort8v*)&Zb[(size_t)(m0 + r) * 512 + sg * 8];
        wq2[it] = *(const ushort8v*)&WoT[(size_t)(n0 + r) * 512 + sg * 8];
    }

    for (int kc = 0; kc < 512; kc += 32) {
        __syncthreads();
#pragma unroll
        for (int it = 0; it < 2; ++it) {
            int r = sr + it * 64;
            *(ushort8v*)&Xl[r * 40 + sg * 8] = xq[it];
            *(ushort8v*)&Wl[r * 40 + sg * 8] = wq2[it];
        }
        __syncthreads();
        if (kc + 32 < 512) {
#pragma unroll
            for (int it = 0; it < 2; ++it) {
                int r = sr + it * 64;
                xq[it]  = *(const ushort8v*)&Zb[(size_t)(m0 + r) * 512 + kc + 32 + sg * 8];
                wq2[it] = *(const ushort8v*)&WoT[(size_t)(n0 + r) * 512 + kc + 32 + sg * 8];
            }
        }
        bf16x8 am[4], an[4];
#pragma unroll
        for (int i = 0; i < 4; ++i)
            am[i] = *(bf16x8*)&Xl[(wm * 64 + i * 16 + ln) * 40 + quad * 8];
#pragma unroll
        for (int j = 0; j < 4; ++j)
            an[j] = *(bf16x8*)&Wl[(wn * 64 + j * 16 + ln) * 40 + quad * 8];
#pragma unroll
        for (int i = 0; i < 4; ++i)
#pragma unroll
            for (int j = 0; j < 4; ++j)
                acc[i][j] = MFMA16(an[j], am[i], acc[i][j]);
    }
#pragma unroll
    for (int i = 0; i < 4; ++i) {
        int m = m0 + wm * 64 + i * 16 + ln;
#pragma unroll
        for (int j = 0; j < 4; ++j) {
            int n = n0 + wn * 64 + j * 16 + quad * 4;
            float4 s;
            s.x = acc[i][j][0]; s.y = acc[i][j][1];
            s.z = acc[i][j][2]; s.w = acc[i][j][3];
            *(float4*)&out[(size_t)m * 512 + n] = s;
        }
    }
}

// ---------------------------------------------------------------- launch
extern "C" void kernel_launch(void* const* d_in, const int* in_sizes, int n_in,
                              void* d_out, int out_size, void* d_ws, size_t ws_size,
                              hipStream_t stream) {
    const float* xs   = (const float*)d_in[0];
    const int*   mask = (const int*)d_in[1];
    const float* Wq   = (const float*)d_in[2];
    const float* Wk   = (const float*)d_in[3];
    const float* Wv   = (const float*)d_in[4];
    const float* Wpos = (const float*)d_in[5];
    const float* Wout = (const float*)d_in[6];
    const float* ub   = (const float*)d_in[7];
    const float* vb   = (const float*)d_in[8];
    float* out = (float*)d_out;

    u16* Qb  = (u16*)d_ws;                   // 4194304
    u16* Kb  = Qb + 4194304;                 // 4194304
    u16* Vtg = Kb + 4194304;                 // 4194304
    u16* P   = Vtg + 4194304;                // 1048576 (8*2047*64 = 1048064 + pad)
    u16* XZ  = P + 1048576;                  // 4194304 (Xb, then reused as Z)
    u16* WT  = XZ + 4194304;                 // 4*262144
    u16* WqT = WT;
    u16* WkT = WT + 262144;
    u16* WvT = WT + 524288;
    u16* WoT = WT + 786432;
    u64* Mp  = (u64*)(WT + 1048576);         // 131072 u64

    prep_kernel<<<4352, 256, 0, stream>>>(xs, XZ, Wq, Wk, Wv, Wout, WT, mask, Mp);
    pos_kernel<<<256, 256, 0, stream>>>(Wpos, P);
    qkv_mfma<<<dim3(64, 12), 256, 0, stream>>>(XZ, WqT, WkT, WvT, Qb, Kb, Vtg);
    attn_mfma<<<1024, 256, 0, stream>>>(Qb, Kb, Vtg, P, Mp, ub, vb, XZ);
    out_mfma<<<dim3(64, 4), 256, 0, stream>>>(XZ, WoT, out);
}

// Round 9
// 331.318 us; speedup vs baseline: 1.1673x; 1.1673x over previous
//
#include <hip/hip_runtime.h>
#include <hip/hip_bf16.h>

// Transformer-XL relative MHA. fp32 in/out, bf16 intermediates in d_ws.
// B=8 T=1024 D_MODEL=512 H=8 DH=64.
// R9: attn = R6 structure (LDS-staged, proven 95us) but each wave handles
// TWO 16-row Q-sets (block = 128 q-rows): K/V/P staging + V-frag reads
// amortized over 2x compute -> ~0.75x LDS ops per unit work (LDS pipe is
// the measured bottleneck). Prob aliases dead Gl storage (same-wave DS ops
// are in-order) to fit 62KB LDS. pos fused into prep; qkv at 3 blocks/CU.
// Rel-shift identity: bd[t,s] = q_v[t] . p[1023 - t + s].

typedef unsigned short u16;
typedef unsigned long long u64;
typedef __attribute__((ext_vector_type(8))) short bf16x8;
typedef __attribute__((ext_vector_type(8))) unsigned short ushort8v;
typedef __attribute__((ext_vector_type(4))) float floatx4;

__device__ __forceinline__ float b2f(u16 u) {
    union { unsigned int i; float f; } x; x.i = ((unsigned int)u) << 16; return x.f;
}
__device__ __forceinline__ u16 f2b(float f) {
    __hip_bfloat16 h = __float2bfloat16(f);
    return *reinterpret_cast<u16*>(&h);
}

#define MFMA16(a, b, c) __builtin_amdgcn_mfma_f32_16x16x32_bf16(a, b, c, 0, 0, 0)

// ---------------------------------------------------------------- prep
// [0,2048): castX ; [2048,2304): castW ; [2304,4352): maskpack ; [4352,4608): pos
__global__ __launch_bounds__(256) void prep_kernel(
    const float* __restrict__ X, u16* __restrict__ Xb,
    const float* __restrict__ W0, const float* __restrict__ W1,
    const float* __restrict__ W2, const float* __restrict__ W3,
    u16* __restrict__ WT,
    const int* __restrict__ mask, u64* __restrict__ Mp,
    const float* __restrict__ Wpos, u16* __restrict__ P)
{
    const int bi = blockIdx.x;
    const int tid = threadIdx.x;
    if (bi < 2048) {
        size_t i = ((size_t)bi * 256 + tid) * 8;
        float4 a = *(const float4*)&X[i];
        float4 b = *(const float4*)&X[i + 4];
        ushort8v s;
        s[0] = f2b(a.x); s[1] = f2b(a.y); s[2] = f2b(a.z); s[3] = f2b(a.w);
        s[4] = f2b(b.x); s[5] = f2b(b.y); s[6] = f2b(b.z); s[7] = f2b(b.w);
        *(ushort8v*)&Xb[i] = s;
    } else if (bi < 2304) {
        __shared__ float t[64][68];
        const int li = bi - 2048;
        const int m = li >> 6;
        const float* src = (m == 0) ? W0 : (m == 1) ? W1 : (m == 2) ? W2 : W3;
        u16* dst = WT + (size_t)m * 262144;
        const int k0 = ((li >> 3) & 7) * 64, n0 = (li & 7) * 64;
        const int r = tid >> 4, c = tid & 15;
#pragma unroll
        for (int rr = 0; rr < 64; rr += 16) {
            float4 v = *(const float4*)&src[(size_t)(k0 + r + rr) * 512 + n0 + 4 * c];
            t[r + rr][4 * c + 0] = v.x;
            t[r + rr][4 * c + 1] = v.y;
            t[r + rr][4 * c + 2] = v.z;
            t[r + rr][4 * c + 3] = v.w;
        }
        __syncthreads();
        const int nrow = tid >> 2, kc = (tid & 3) * 16;
        ushort8v s0, s1;
#pragma unroll
        for (int e = 0; e < 8; ++e) {
            s0[e] = f2b(t[kc + e][nrow]);
            s1[e] = f2b(t[kc + 8 + e][nrow]);
        }
        *(ushort8v*)&dst[(size_t)(n0 + nrow) * 512 + k0 + kc] = s0;
        *(ushort8v*)&dst[(size_t)(n0 + nrow) * 512 + k0 + kc + 8] = s1;
    } else if (bi < 4352) {
        const int lane = tid & 63, w = tid >> 6;
        const int row = (bi - 2304) * 4 + w;
#pragma unroll
        for (int j = 0; j < 16; ++j) {
            int v = mask[(size_t)row * 1024 + j * 64 + lane];
            u64 bits = __ballot(v != 0);
            if (lane == j) Mp[(size_t)row * 16 + j] = bits;
        }
    } else {
        // ---- pos: P[h][l][d] = sum_k pe[l][k]*Wpos[k][h*64+d]
        __shared__ float pe[8][512];
        const int l0 = (bi - 4352) * 8;
        float invf = expf(-9.210340371976184f * ((float)tid / 256.0f));
        for (int il = 0; il < 8; ++il) {
            int l = l0 + il; if (l > 2046) l = 2046;
            float ang = (float)(l - 1023) * invf;
            pe[il][2 * tid]     = sinf(ang);
            pe[il][2 * tid + 1] = cosf(ang);
        }
        __syncthreads();
        float acc[8][2];
        for (int il = 0; il < 8; ++il) { acc[il][0] = 0.f; acc[il][1] = 0.f; }
        for (int k = 0; k < 512; ++k) {
            float w0 = Wpos[k * 512 + tid];
            float w1 = Wpos[k * 512 + tid + 256];
#pragma unroll
            for (int il = 0; il < 8; ++il) {
                float pk = pe[il][k];
                acc[il][0] = fmaf(pk, w0, acc[il][0]);
                acc[il][1] = fmaf(pk, w1, acc[il][1]);
            }
        }
        for (int il = 0; il < 8; ++il) {
            int l = l0 + il; if (l >= 2047) break;
            int c0 = tid, c1 = tid + 256;
            P[((size_t)(c0 >> 6) * 2047 + l) * 64 + (c0 & 63)] = f2b(acc[il][0]);
            P[((size_t)(c1 >> 6) * 2047 + l) * 64 + (c1 & 63)] = f2b(acc[il][1]);
        }
    }
}

// ---------------------------------------------------------------- qkv MFMA
// grid (64, 12): x -> 128 rows of xs; y: 0-3 Q, 4-7 K, 8-11 V (n0=(y&3)*128).
__global__ __launch_bounds__(256, 3) void qkv_mfma(
    const u16* __restrict__ Xb, const u16* __restrict__ WqT,
    const u16* __restrict__ WkT, const u16* __restrict__ WvT,
    u16* __restrict__ Qb, u16* __restrict__ Kb, u16* __restrict__ Vtg)
{
    __shared__ u16 Xl[128 * 40];
    __shared__ u16 Wl[128 * 40];
    const int tid = threadIdx.x;
    const int lane = tid & 63, w = tid >> 6;
    const int quad = lane >> 4, ln = lane & 15;
    const int wm = w & 1, wn = w >> 1;

    const int m0 = blockIdx.x * 128;
    const int sel = blockIdx.y >> 2;
    const int n0 = (blockIdx.y & 3) * 128;
    const u16* WT = (sel == 0) ? WqT : (sel == 1) ? WkT : WvT;
    const int b = m0 >> 10, tbase = m0 & 1023;

    const int sr = tid >> 2, sg = tid & 3;

    floatx4 acc[4][4];
#pragma unroll
    for (int i = 0; i < 4; ++i)
#pragma unroll
        for (int j = 0; j < 4; ++j) acc[i][j] = (floatx4){0.f, 0.f, 0.f, 0.f};

    ushort8v xq[2], wq2[2];
#pragma unroll
    for (int it = 0; it < 2; ++it) {
        int r = sr + it * 64;
        xq[it]  = *(const ushort8v*)&Xb[(size_t)(m0 + r) * 512 + sg * 8];
        wq2[it] = *(const ushort8v*)&WT[(size_t)(n0 + r) * 512 + sg * 8];
    }

    for (int kc = 0; kc < 512; kc += 32) {
        __syncthreads();
#pragma unroll
        for (int it = 0; it < 2; ++it) {
            int r = sr + it * 64;
            *(ushort8v*)&Xl[r * 40 + sg * 8] = xq[it];
            *(ushort8v*)&Wl[r * 40 + sg * 8] = wq2[it];
        }
        __syncthreads();
        if (kc + 32 < 512) {
#pragma unroll
            for (int it = 0; it < 2; ++it) {
                int r = sr + it * 64;
                xq[it]  = *(const ushort8v*)&Xb[(size_t)(m0 + r) * 512 + kc + 32 + sg * 8];
                wq2[it] = *(const ushort8v*)&WT[(size_t)(n0 + r) * 512 + kc + 32 + sg * 8];
            }
        }
        bf16x8 am[4], an[4];
#pragma unroll
        for (int i = 0; i < 4; ++i)
            am[i] = *(bf16x8*)&Xl[(wm * 64 + i * 16 + ln) * 40 + quad * 8];
#pragma unroll
        for (int j = 0; j < 4; ++j)
            an[j] = *(bf16x8*)&Wl[(wn * 64 + j * 16 + ln) * 40 + quad * 8];
        if (sel < 2) {
#pragma unroll
            for (int i = 0; i < 4; ++i)
#pragma unroll
                for (int j = 0; j < 4; ++j)
                    acc[i][j] = MFMA16(an[j], am[i], acc[i][j]);
        } else {
#pragma unroll
            for (int i = 0; i < 4; ++i)
#pragma unroll
                for (int j = 0; j < 4; ++j)
                    acc[i][j] = MFMA16(am[i], an[j], acc[i][j]);
        }
    }
    if (sel < 2) {
        u16* dst = (sel == 0) ? Qb : Kb;
#pragma unroll
        for (int i = 0; i < 4; ++i) {
            int t = tbase + wm * 64 + i * 16 + ln;
#pragma unroll
            for (int j = 0; j < 4; ++j) {
                int n = n0 + wn * 64 + j * 16 + quad * 4;
                int h = n >> 6, d = n & 63;
                ushort4 s;
                s.x = f2b(acc[i][j][0]); s.y = f2b(acc[i][j][1]);
                s.z = f2b(acc[i][j][2]); s.w = f2b(acc[i][j][3]);
                *(ushort4*)&dst[(((size_t)b * 8 + h) * 1024 + t) * 64 + d] = s;
            }
        }
    } else {
#pragma unroll
        for (int i = 0; i < 4; ++i) {
            int t4 = tbase + wm * 64 + i * 16 + quad * 4;
#pragma unroll
            for (int j = 0; j < 4; ++j) {
                int n = n0 + wn * 64 + j * 16 + ln;
                int h = n >> 6, d = n & 63;
                ushort4 s;
                s.x = f2b(acc[i][j][0]); s.y = f2b(acc[i][j][1]);
                s.z = f2b(acc[i][j][2]); s.w = f2b(acc[i][j][3]);
                *(ushort4*)&Vtg[(((size_t)b * 8 + h) * 64 + d) * 1024 + t4] = s;
            }
        }
    }
}

// ---------------------------------------------------------------- attention
__device__ __forceinline__ bf16x8 addbias(bf16x8 q, const float* __restrict__ bias) {
    float4 a = *(const float4*)&bias[0];
    float4 b = *(const float4*)&bias[4];
    bf16x8 r;
    r[0] = (short)f2b(b2f((u16)q[0]) + a.x);
    r[1] = (short)f2b(b2f((u16)q[1]) + a.y);
    r[2] = (short)f2b(b2f((u16)q[2]) + a.z);
    r[3] = (short)f2b(b2f((u16)q[3]) + a.w);
    r[4] = (short)f2b(b2f((u16)q[4]) + b.x);
    r[5] = (short)f2b(b2f((u16)q[5]) + b.y);
    r[6] = (short)f2b(b2f((u16)q[6]) + b.z);
    r[7] = (short)f2b(b2f((u16)q[7]) + b.w);
    return r;
}

// Block = (b, h, 128 q-rows) = 4 waves x 2 sets x 16 rows. S-chunks of 64.
// Pband rows rb = 112 - 64c - 16w + j, staged rows [0,192), lbase=896-t0+s0.
// WaveBuf: Gl f32 [tt][j] (stride 80) aliased by Prob u16 [tt][ss] (stride 72)
// -- Gl fully consumed by the score phase before Prob is written; same-wave
// DS ops execute in order.
__global__ __launch_bounds__(256, 2) void attn_mfma(
    const u16* __restrict__ Qb,
    const u16* __restrict__ Kb, const u16* __restrict__ Vtg,
    const u16* __restrict__ P, const u64* __restrict__ Mp,
    const float* __restrict__ ub, const float* __restrict__ vb,
    u16* __restrict__ Z)
{
    __shared__ u16 Klds[64 * 72];                  // [s][d] stride 72
    __shared__ u16 Vtlds[64 * 72];                 // [d][s] stride 72
    __shared__ u16 Pb[192 * 64];                   // [rb][d] XOR-swizzled 16B blocks
    __shared__ __align__(16) char WaveBuf[4][16 * 80 * 4];

    const int tid  = threadIdx.x;
    const int lane = tid & 63;
    const int w    = tid >> 6;
    const int quad = lane >> 4;
    const int ln   = lane & 15;

    const int bid = blockIdx.x;                    // 512 blocks
    const int xg  = bid & 7;
    const int idx = bid >> 3;                      // 0..63
    const int bh_i = xg * 8 + (idx >> 3);
    const int t0 = (idx & 7) << 7;                 // *128
    const int h  = bh_i & 7;
    const int b  = bh_i >> 3;
    const size_t bh  = (size_t)bh_i * 1024;
    const size_t bhd = (size_t)bh_i * 64;
    size_t mprow[2];
    mprow[0] = ((size_t)b * 1024 + t0 + 16 * w + ln) * 16;
    mprow[1] = ((size_t)b * 1024 + t0 + 64 + 16 * w + ln) * 16;

    // register B-fragments (2 sets) with bias add
    bf16x8 qu0[2], qu1[2], qv0[2], qv1[2];
#pragma unroll
    for (int c = 0; c < 2; ++c) {
        const size_t qoff = (bh + t0 + 64 * c + 16 * w + ln) * 64;
        bf16x8 q0 = *(const bf16x8*)&Qb[qoff + quad * 8];
        bf16x8 q1 = *(const bf16x8*)&Qb[qoff + 32 + quad * 8];
        qu0[c] = addbias(q0, &ub[h * 64 + quad * 8]);
        qu1[c] = addbias(q1, &ub[h * 64 + 32 + quad * 8]);
        qv0[c] = addbias(q0, &vb[h * 64 + quad * 8]);
        qv1[c] = addbias(q1, &vb[h * 64 + 32 + quad * 8]);
    }

    floatx4 O[2][4];
#pragma unroll
    for (int c = 0; c < 2; ++c)
#pragma unroll
        for (int dt = 0; dt < 4; ++dt) O[c][dt] = (floatx4){0.f, 0.f, 0.f, 0.f};
    float m_run[2] = {-3.0e38f, -3.0e38f}, l_run[2] = {0.f, 0.f};

    float* gw = (float*)&WaveBuf[w][0];
    u16*  pw  = (u16*)&WaveBuf[w][0];

    const int str = tid >> 3, stg = tid & 7;       // staging coords
    ushort8v kq[2], vq[2], pq[6];

#define LOAD_CHUNK(S0)                                                            \
    {                                                                             \
        _Pragma("unroll")                                                         \
        for (int it = 0; it < 2; ++it) {                                          \
            int r = str + it * 32;                                                \
            kq[it] = *(const ushort8v*)&Kb[(bh + (S0) + r) * 64 + stg * 8];       \
            vq[it] = *(const ushort8v*)&Vtg[(bhd + r) * 1024 + (S0) + stg * 8];   \
        }                                                                         \
        const int lb0 = 896 - t0 + (S0);                                          \
        _Pragma("unroll")                                                         \
        for (int it = 0; it < 6; ++it) {                                          \
            int r = str + it * 32;                                                \
            int l = lb0 + r; if (l > 2046) l = 2046;                              \
            pq[it] = *(const ushort8v*)&P[((size_t)h * 2047 + l) * 64 + stg * 8]; \
        }                                                                         \
    }

    LOAD_CHUNK(0)

    for (int s0 = 0; s0 < 1024; s0 += 64) {
        __syncthreads();
#pragma unroll
        for (int it = 0; it < 2; ++it) {
            int r = str + it * 32;
            *(ushort8v*)&Klds[r * 72 + stg * 8] = kq[it];
            *(ushort8v*)&Vtlds[r * 72 + stg * 8] = vq[it];
        }
#pragma unroll
        for (int it = 0; it < 6; ++it) {
            int r = str + it * 32;
            *(ushort8v*)&Pb[r * 64 + ((stg ^ (r & 7)) << 3)] = pq[it];
        }
        __syncthreads();
        if (s0 + 64 < 1024) LOAD_CHUNK(s0 + 64)

        // hoist V B-frags (shared by both sets)
        bf16x8 vf0[4], vf1[4];
#pragma unroll
        for (int dt = 0; dt < 4; ++dt) {
            int vr = dt * 16 + ln;
            vf0[dt] = *(bf16x8*)&Vtlds[vr * 72 + quad * 8];
            vf1[dt] = *(bf16x8*)&Vtlds[vr * 72 + 32 + quad * 8];
        }

#pragma unroll
        for (int c = 0; c < 2; ++c) {
            const u64 bits = Mp[mprow[c] + (s0 >> 6)];
            // BD: G^T[j][tt] = Pband . Qv^T  (j = ss - tt + 15)
            const int rb0 = 112 - 64 * c - 16 * w;
#pragma unroll
            for (int jt = 0; jt < 5; ++jt) {
                int rb = rb0 + jt * 16 + ln;
                bf16x8 a0 = *(bf16x8*)&Pb[rb * 64 + ((quad ^ (rb & 7)) << 3)];
                bf16x8 a1 = *(bf16x8*)&Pb[rb * 64 + (((4 + quad) ^ (rb & 7)) << 3)];
                floatx4 g = {0.f, 0.f, 0.f, 0.f};
                g = MFMA16(a0, qv0[c], g);
                g = MFMA16(a1, qv1[c], g);
                *(floatx4*)&gw[ln * 80 + jt * 16 + quad * 4] = g;
            }
            // AC: S^T[ss][tt] = K . Qu^T
            floatx4 cac[4];
#pragma unroll
            for (int st = 0; st < 4; ++st) {
                int kr = st * 16 + ln;
                bf16x8 a0 = *(bf16x8*)&Klds[kr * 72 + quad * 8];
                bf16x8 a1 = *(bf16x8*)&Klds[kr * 72 + 32 + quad * 8];
                floatx4 cc = {0.f, 0.f, 0.f, 0.f};
                cc = MFMA16(a0, qu0[c], cc);
                cc = MFMA16(a1, qu1[c], cc);
                cac[st] = cc;
            }
            // scores + online softmax (lane owns col tt = ln)
            float sc[4][4];
            float cmax = -3.0e38f;
#pragma unroll
            for (int st = 0; st < 4; ++st) {
                int j0 = st * 16 + quad * 4 + 15 - ln;
#pragma unroll
                for (int r = 0; r < 4; ++r) {
                    float v = (cac[st][r] + gw[ln * 80 + j0 + r]) * 0.125f;
                    int ss = st * 16 + quad * 4 + r;
                    v = ((bits >> ss) & 1ull) ? v : -1.0e30f;
                    sc[st][r] = v;
                    cmax = fmaxf(cmax, v);
                }
            }
            cmax = fmaxf(cmax, __shfl_xor(cmax, 16));
            cmax = fmaxf(cmax, __shfl_xor(cmax, 32));
            float m_new = fmaxf(m_run[c], cmax);
            float alpha = __expf(m_run[c] - m_new);
            float psum = 0.f;
#pragma unroll
            for (int st = 0; st < 4; ++st) {
                float p0 = __expf(sc[st][0] - m_new);
                float p1 = __expf(sc[st][1] - m_new);
                float p2 = __expf(sc[st][2] - m_new);
                float p3 = __expf(sc[st][3] - m_new);
                psum += (p0 + p1) + (p2 + p3);
                ushort4 pk;
                pk.x = f2b(p0); pk.y = f2b(p1); pk.z = f2b(p2); pk.w = f2b(p3);
                *(ushort4*)&pw[ln * 72 + st * 16 + quad * 4] = pk;   // aliases gw (dead)
            }
            psum += __shfl_xor(psum, 16);
            psum += __shfl_xor(psum, 32);
            l_run[c] = l_run[c] * alpha + psum;
            m_run[c] = m_new;
            float a0s = __shfl(alpha, quad * 4 + 0);
            float a1s = __shfl(alpha, quad * 4 + 1);
            float a2s = __shfl(alpha, quad * 4 + 2);
            float a3s = __shfl(alpha, quad * 4 + 3);
#pragma unroll
            for (int dt = 0; dt < 4; ++dt) {
                O[c][dt][0] *= a0s; O[c][dt][1] *= a1s;
                O[c][dt][2] *= a2s; O[c][dt][3] *= a3s;
            }
            // PV
            bf16x8 pa0 = *(bf16x8*)&pw[ln * 72 + quad * 8];
            bf16x8 pa1 = *(bf16x8*)&pw[ln * 72 + 32 + quad * 8];
#pragma unroll
            for (int dt = 0; dt < 4; ++dt) {
                O[c][dt] = MFMA16(pa0, vf0[dt], O[c][dt]);
                O[c][dt] = MFMA16(pa1, vf1[dt], O[c][dt]);
            }
        }
    }
#pragma unroll
    for (int c = 0; c < 2; ++c) {
        float li[4];
#pragma unroll
        for (int r = 0; r < 4; ++r) li[r] = 1.0f / __shfl(l_run[c], quad * 4 + r);
#pragma unroll
        for (int r = 0; r < 4; ++r) {
            size_t zo = ((size_t)b * 1024 + t0 + 64 * c + 16 * w + quad * 4 + r) * 512
                      + h * 64 + ln;
            Z[zo + 0]  = f2b(O[c][0][r] * li[r]);
            Z[zo + 16] = f2b(O[c][1][r] * li[r]);
            Z[zo + 32] = f2b(O[c][2][r] * li[r]);
            Z[zo + 48] = f2b(O[c][3][r] * li[r]);
        }
    }
}

// ---------------------------------------------------------------- out MFMA
__global__ __launch_bounds__(256, 2) void out_mfma(
    const u16* __restrict__ Zb, const u16* __restrict__ WoT,
    float* __restrict__ out)
{
    __shared__ u16 Xl[128 * 40];
    __shared__ u16 Wl[128 * 40];
    const int tid = threadIdx.x;
    const int lane = tid & 63, w = tid >> 6;
    const int quad = lane >> 4, ln = lane & 15;
    const int wm = w & 1, wn = w >> 1;
    const int m0 = blockIdx.x * 128;
    const int n0 = blockIdx.y * 128;
    const int sr = tid >> 2, sg = tid & 3;

    floatx4 acc[4][4];
#pragma unroll
    for (int i = 0; i < 4; ++i)
#pragma unroll
        for (int j = 0; j < 4; ++j) acc[i][j] = (floatx4){0.f, 0.f, 0.f, 0.f};

    ushort8v xq[2], wq2[2];
#pragma unroll
    for (int it = 0; it < 2; ++it) {
        int r = sr + it * 64;
        xq[it]  = *(const ushort8v*)&Zb[(size_t)(m0 + r) * 512 + sg * 8];
        wq2[it] = *(const ushort8v*)&WoT[(size_t)(n0 + r) * 512 + sg * 8];
    }

    for (int kc = 0; kc < 512; kc += 32) {
        __syncthreads();
#pragma unroll
        for (int it = 0; it < 2; ++it) {
            int r = sr + it * 64;
            *(ushort8v*)&Xl[r * 40 + sg * 8] = xq[it];
            *(ushort8v*)&Wl[r * 40 + sg * 8] = wq2[it];
        }
        __syncthreads();
        if (kc + 32 < 512) {
#pragma unroll
            for (int it = 0; it < 2; ++it) {
                int r = sr + it * 64;
                xq[it]  = *(const ushort8v*)&Zb[(size_t)(m0 + r) * 512 + kc + 32 + sg * 8];
                wq2[it] = *(const ushort8v*)&WoT[(size_t)(n0 + r) * 512 + kc + 32 + sg * 8];
            }
        }
        bf16x8 am[4], an[4];
#pragma unroll
        for (int i = 0; i < 4; ++i)
            am[i] = *(bf16x8*)&Xl[(wm * 64 + i * 16 + ln) * 40 + quad * 8];
#pragma unroll
        for (int j = 0; j < 4; ++j)
            an[j] = *(bf16x8*)&Wl[(wn * 64 + j * 16 + ln) * 40 + quad * 8];
#pragma unroll
        for (int i = 0; i < 4; ++i)
#pragma unroll
            for (int j = 0; j < 4; ++j)
                acc[i][j] = MFMA16(an[j], am[i], acc[i][j]);
    }
#pragma unroll
    for (int i = 0; i < 4; ++i) {
        int m = m0 + wm * 64 + i * 16 + ln;
#pragma unroll
        for (int j = 0; j < 4; ++j) {
            int n = n0 + wn * 64 + j * 16 + quad * 4;
            float4 s;
            s.x = acc[i][j][0]; s.y = acc[i][j][1];
            s.z = acc[i][j][2]; s.w = acc[i][j][3];
            *(float4*)&out[(size_t)m * 512 + n] = s;
        }
    }
}

// ---------------------------------------------------------------- launch
extern "C" void kernel_launch(void* const* d_in, const int* in_sizes, int n_in,
                              void* d_out, int out_size, void* d_ws, size_t ws_size,
                              hipStream_t stream) {
    const float* xs   = (const float*)d_in[0];
    const int*   mask = (const int*)d_in[1];
    const float* Wq   = (const float*)d_in[2];
    const float* Wk   = (const float*)d_in[3];
    const float* Wv   = (const float*)d_in[4];
    const float* Wpos = (const float*)d_in[5];
    const float* Wout = (const float*)d_in[6];
    const float* ub   = (const float*)d_in[7];
    const float* vb   = (const float*)d_in[8];
    float* out = (float*)d_out;

    u16* Qb  = (u16*)d_ws;                   // 4194304
    u16* Kb  = Qb + 4194304;                 // 4194304
    u16* Vtg = Kb + 4194304;                 // 4194304
    u16* P   = Vtg + 4194304;                // 1048576 (8*2047*64 = 1048064 + pad)
    u16* XZ  = P + 1048576;                  // 4194304 (Xb, then reused as Z)
    u16* WT  = XZ + 4194304;                 // 4*262144
    u16* WqT = WT;
    u16* WkT = WT + 262144;
    u16* WvT = WT + 524288;
    u16* WoT = WT + 786432;
    u64* Mp  = (u64*)(WT + 1048576);         // 131072 u64

    prep_kernel<<<4608, 256, 0, stream>>>(xs, XZ, Wq, Wk, Wv, Wout, WT, mask, Mp,
                                          Wpos, P);
    qkv_mfma<<<dim3(64, 12), 256, 0, stream>>>(XZ, WqT, WkT, WvT, Qb, Kb, Vtg);
    attn_mfma<<<512, 256, 0, stream>>>(Qb, Kb, Vtg, P, Mp, ub, vb, XZ);
    out_mfma<<<dim3(64, 4), 256, 0, stream>>>(XZ, WoT, out);
}

// Round 10
// 232.909 us; speedup vs baseline: 1.6605x; 1.4225x over previous
//
#include <hip/hip_runtime.h>
#include <hip/hip_bf16.h>

// Transformer-XL relative MHA. fp32 in/out, bf16 intermediates in d_ws.
// B=8 T=1024 D_MODEL=512 H=8 DH=64.
// R10: pos encoding GEMM moved to MFMA (pe generated bf16 in prep; P =
// pe @ Wpos folded into qkv_mfma grid y==12) -- the old serial-VALU pos
// loop was ~90us, hidden below attn in top-5 since R4. P rows now stride
// 2048 (same 1MB, pow2 index, no clamps). qkv back to (256,2).
// attn = R9 two-Q-set structure (<=91us measured).
// Rel-shift identity: bd[t,s] = q_v[t] . p[1023 - t + s].

typedef unsigned short u16;
typedef unsigned long long u64;
typedef __attribute__((ext_vector_type(8))) short bf16x8;
typedef __attribute__((ext_vector_type(8))) unsigned short ushort8v;
typedef __attribute__((ext_vector_type(4))) float floatx4;

__device__ __forceinline__ float b2f(u16 u) {
    union { unsigned int i; float f; } x; x.i = ((unsigned int)u) << 16; return x.f;
}
__device__ __forceinline__ u16 f2b(float f) {
    __hip_bfloat16 h = __float2bfloat16(f);
    return *reinterpret_cast<u16*>(&h);
}

#define MFMA16(a, b, c) __builtin_amdgcn_mfma_f32_16x16x32_bf16(a, b, c, 0, 0, 0)

// ---------------------------------------------------------------- prep
// [0,2048): castX ; [2048,2368): castW x5 ; [2368,4416): maskpack ;
// [4416,4928): pe-gen (bf16 sinusoid table, 2048 rows x 512)
__global__ __launch_bounds__(256) void prep_kernel(
    const float* __restrict__ X, u16* __restrict__ Xb,
    const float* __restrict__ W0, const float* __restrict__ W1,
    const float* __restrict__ W2, const float* __restrict__ W3,
    const float* __restrict__ W4, u16* __restrict__ WT,
    const int* __restrict__ mask, u64* __restrict__ Mp,
    u16* __restrict__ Peb)
{
    const int bi = blockIdx.x;
    const int tid = threadIdx.x;
    if (bi < 2048) {
        size_t i = ((size_t)bi * 256 + tid) * 8;
        float4 a = *(const float4*)&X[i];
        float4 b = *(const float4*)&X[i + 4];
        ushort8v s;
        s[0] = f2b(a.x); s[1] = f2b(a.y); s[2] = f2b(a.z); s[3] = f2b(a.w);
        s[4] = f2b(b.x); s[5] = f2b(b.y); s[6] = f2b(b.z); s[7] = f2b(b.w);
        *(ushort8v*)&Xb[i] = s;
    } else if (bi < 2368) {
        __shared__ float t[64][68];
        const int li = bi - 2048;
        const int m = li >> 6;
        const float* src = (m == 0) ? W0 : (m == 1) ? W1 : (m == 2) ? W2
                         : (m == 3) ? W3 : W4;
        u16* dst = WT + (size_t)m * 262144;
        const int sub = li & 63;
        const int k0 = ((sub >> 3) & 7) * 64, n0 = (sub & 7) * 64;
        const int r = tid >> 4, c = tid & 15;
#pragma unroll
        for (int rr = 0; rr < 64; rr += 16) {
            float4 v = *(const float4*)&src[(size_t)(k0 + r + rr) * 512 + n0 + 4 * c];
            t[r + rr][4 * c + 0] = v.x;
            t[r + rr][4 * c + 1] = v.y;
            t[r + rr][4 * c + 2] = v.z;
            t[r + rr][4 * c + 3] = v.w;
        }
        __syncthreads();
        const int nrow = tid >> 2, kc = (tid & 3) * 16;
        ushort8v s0, s1;
#pragma unroll
        for (int e = 0; e < 8; ++e) {
            s0[e] = f2b(t[kc + e][nrow]);
            s1[e] = f2b(t[kc + 8 + e][nrow]);
        }
        *(ushort8v*)&dst[(size_t)(n0 + nrow) * 512 + k0 + kc] = s0;
        *(ushort8v*)&dst[(size_t)(n0 + nrow) * 512 + k0 + kc + 8] = s1;
    } else if (bi < 4416) {
        const int lane = tid & 63, w = tid >> 6;
        const int row = (bi - 2368) * 4 + w;
#pragma unroll
        for (int j = 0; j < 16; ++j) {
            int v = mask[(size_t)row * 1024 + j * 64 + lane];
            u64 bits = __ballot(v != 0);
            if (lane == j) Mp[(size_t)row * 16 + j] = bits;
        }
    } else {
        // ---- pe-gen: row l (wave-per-row), lane covers 8 consecutive k.
        // pe[l][2i] = sin(pos*invf_i), pe[l][2i+1] = cos(...), pos=min(l,2046)-1023
        const int lane = tid & 63, w = tid >> 6;
        const int l = (bi - 4416) * 4 + w;             // 0..2047
        const int lc = (l > 2046) ? 2046 : l;
        const float pos = (float)(lc - 1023);
        ushort8v s;
#pragma unroll
        for (int e = 0; e < 8; ++e) {
            int k = (lane << 3) + e;
            int i = k >> 1;
            float invf = expf(-0.035977892f * (float)i);   // ln(1e4)/256
            float ang = pos * invf;
            float v = (k & 1) ? cosf(ang) : sinf(ang);
            s[e] = f2b(v);
        }
        *(ushort8v*)&Peb[(size_t)l * 512 + (lane << 3)] = s;
    }
}

// ---------------------------------------------------------------- qkv+pos MFMA
// grid (64, 13): y<12 -> QKV (y: 0-3 Q, 4-7 K, 8-11 V; n0=(y&3)*128,
// m0=x*128 over xs). y==12 -> pos GEMM: m0=(x>>2)*128 over pe (M=2048),
// n0=(x&3)*128; writes P[h][l(stride2048)][d].
__global__ __launch_bounds__(256, 2) void qkv_mfma(
    const u16* __restrict__ Xb, const u16* __restrict__ WqT,
    const u16* __restrict__ WkT, const u16* __restrict__ WvT,
    const u16* __restrict__ Peb, const u16* __restrict__ WposT,
    u16* __restrict__ Qb, u16* __restrict__ Kb, u16* __restrict__ Vtg,
    u16* __restrict__ Pg)
{
    __shared__ u16 Xl[128 * 40];
    __shared__ u16 Wl[128 * 40];
    const int tid = threadIdx.x;
    const int lane = tid & 63, w = tid >> 6;
    const int quad = lane >> 4, ln = lane & 15;
    const int wm = w & 1, wn = w >> 1;

    const int yy = blockIdx.y;
    int sel, m0, n0;
    const u16 *Ap, *Bp;
    if (yy < 12) {
        sel = yy >> 2; n0 = (yy & 3) * 128; m0 = blockIdx.x * 128;
        Ap = Xb; Bp = (sel == 0) ? WqT : (sel == 1) ? WkT : WvT;
    } else {
        sel = 3; m0 = (blockIdx.x >> 2) * 128; n0 = (blockIdx.x & 3) * 128;
        Ap = Peb; Bp = WposT;
    }
    const int b = (m0 >> 10) & 7, tbase = m0 & 1023;

    const int sr = tid >> 2, sg = tid & 3;

    floatx4 acc[4][4];
#pragma unroll
    for (int i = 0; i < 4; ++i)
#pragma unroll
        for (int j = 0; j < 4; ++j) acc[i][j] = (floatx4){0.f, 0.f, 0.f, 0.f};

    ushort8v xq[2], wq2[2];
#pragma unroll
    for (int it = 0; it < 2; ++it) {
        int r = sr + it * 64;
        xq[it]  = *(const ushort8v*)&Ap[(size_t)(m0 + r) * 512 + sg * 8];
        wq2[it] = *(const ushort8v*)&Bp[(size_t)(n0 + r) * 512 + sg * 8];
    }

    for (int kc = 0; kc < 512; kc += 32) {
        __syncthreads();
#pragma unroll
        for (int it = 0; it < 2; ++it) {
            int r = sr + it * 64;
            *(ushort8v*)&Xl[r * 40 + sg * 8] = xq[it];
            *(ushort8v*)&Wl[r * 40 + sg * 8] = wq2[it];
        }
        __syncthreads();
        if (kc + 32 < 512) {
#pragma unroll
            for (int it = 0; it < 2; ++it) {
                int r = sr + it * 64;
                xq[it]  = *(const ushort8v*)&Ap[(size_t)(m0 + r) * 512 + kc + 32 + sg * 8];
                wq2[it] = *(const ushort8v*)&Bp[(size_t)(n0 + r) * 512 + kc + 32 + sg * 8];
            }
        }
        bf16x8 am[4], an[4];
#pragma unroll
        for (int i = 0; i < 4; ++i)
            am[i] = *(bf16x8*)&Xl[(wm * 64 + i * 16 + ln) * 40 + quad * 8];
#pragma unroll
        for (int j = 0; j < 4; ++j)
            an[j] = *(bf16x8*)&Wl[(wn * 64 + j * 16 + ln) * 40 + quad * 8];
        if (sel != 2) {
#pragma unroll
            for (int i = 0; i < 4; ++i)
#pragma unroll
                for (int j = 0; j < 4; ++j)
                    acc[i][j] = MFMA16(an[j], am[i], acc[i][j]);
        } else {
#pragma unroll
            for (int i = 0; i < 4; ++i)
#pragma unroll
                for (int j = 0; j < 4; ++j)
                    acc[i][j] = MFMA16(am[i], an[j], acc[i][j]);
        }
    }
    if (sel < 2) {
        u16* dst = (sel == 0) ? Qb : Kb;
#pragma unroll
        for (int i = 0; i < 4; ++i) {
            int t = tbase + wm * 64 + i * 16 + ln;
#pragma unroll
            for (int j = 0; j < 4; ++j) {
                int n = n0 + wn * 64 + j * 16 + quad * 4;
                int h = n >> 6, d = n & 63;
                ushort4 s;
                s.x = f2b(acc[i][j][0]); s.y = f2b(acc[i][j][1]);
                s.z = f2b(acc[i][j][2]); s.w = f2b(acc[i][j][3]);
                *(ushort4*)&dst[(((size_t)b * 8 + h) * 1024 + t) * 64 + d] = s;
            }
        }
    } else if (sel == 2) {
#pragma unroll
        for (int i = 0; i < 4; ++i) {
            int t4 = tbase + wm * 64 + i * 16 + quad * 4;
#pragma unroll
            for (int j = 0; j < 4; ++j) {
                int n = n0 + wn * 64 + j * 16 + ln;
                int h = n >> 6, d = n & 63;
                ushort4 s;
                s.x = f2b(acc[i][j][0]); s.y = f2b(acc[i][j][1]);
                s.z = f2b(acc[i][j][2]); s.w = f2b(acc[i][j][3]);
                *(ushort4*)&Vtg[(((size_t)b * 8 + h) * 64 + d) * 1024 + t4] = s;
            }
        }
    } else {
        // pos: P[(h*2048 + l)*64 + d]
#pragma unroll
        for (int i = 0; i < 4; ++i) {
            int l = m0 + wm * 64 + i * 16 + ln;
#pragma unroll
            for (int j = 0; j < 4; ++j) {
                int n = n0 + wn * 64 + j * 16 + quad * 4;
                int h = n >> 6, d = n & 63;
                ushort4 s;
                s.x = f2b(acc[i][j][0]); s.y = f2b(acc[i][j][1]);
                s.z = f2b(acc[i][j][2]); s.w = f2b(acc[i][j][3]);
                *(ushort4*)&Pg[(((size_t)h << 11) + l) * 64 + d] = s;
            }
        }
    }
}

// ---------------------------------------------------------------- attention
__device__ __forceinline__ bf16x8 addbias(bf16x8 q, const float* __restrict__ bias) {
    float4 a = *(const float4*)&bias[0];
    float4 b = *(const float4*)&bias[4];
    bf16x8 r;
    r[0] = (short)f2b(b2f((u16)q[0]) + a.x);
    r[1] = (short)f2b(b2f((u16)q[1]) + a.y);
    r[2] = (short)f2b(b2f((u16)q[2]) + a.z);
    r[3] = (short)f2b(b2f((u16)q[3]) + a.w);
    r[4] = (short)f2b(b2f((u16)q[4]) + b.x);
    r[5] = (short)f2b(b2f((u16)q[5]) + b.y);
    r[6] = (short)f2b(b2f((u16)q[6]) + b.z);
    r[7] = (short)f2b(b2f((u16)q[7]) + b.w);
    return r;
}

// Block = (b, h, 128 q-rows) = 4 waves x 2 sets x 16 rows. S-chunks of 64.
// Pband rows rb = 112 - 64c - 16w + j, staged rows [0,192), lbase=896-t0+s0
// (l in [0,2047], P stride 2048 -> no clamp). WaveBuf: Gl f32 aliased by
// Prob u16 (Gl dead before Prob writes; same-wave DS ops in order).
__global__ __launch_bounds__(256, 2) void attn_mfma(
    const u16* __restrict__ Qb,
    const u16* __restrict__ Kb, const u16* __restrict__ Vtg,
    const u16* __restrict__ P, const u64* __restrict__ Mp,
    const float* __restrict__ ub, const float* __restrict__ vb,
    u16* __restrict__ Z)
{
    __shared__ u16 Klds[64 * 72];
    __shared__ u16 Vtlds[64 * 72];
    __shared__ u16 Pb[192 * 64];
    __shared__ __align__(16) char WaveBuf[4][16 * 80 * 4];

    const int tid  = threadIdx.x;
    const int lane = tid & 63;
    const int w    = tid >> 6;
    const int quad = lane >> 4;
    const int ln   = lane & 15;

    const int bid = blockIdx.x;                    // 512 blocks
    const int xg  = bid & 7;
    const int idx = bid >> 3;
    const int bh_i = xg * 8 + (idx >> 3);
    const int t0 = (idx & 7) << 7;
    const int h  = bh_i & 7;
    const int b  = bh_i >> 3;
    const size_t bh  = (size_t)bh_i * 1024;
    const size_t bhd = (size_t)bh_i * 64;
    size_t mprow[2];
    mprow[0] = ((size_t)b * 1024 + t0 + 16 * w + ln) * 16;
    mprow[1] = ((size_t)b * 1024 + t0 + 64 + 16 * w + ln) * 16;

    bf16x8 qu0[2], qu1[2], qv0[2], qv1[2];
#pragma unroll
    for (int c = 0; c < 2; ++c) {
        const size_t qoff = (bh + t0 + 64 * c + 16 * w + ln) * 64;
        bf16x8 q0 = *(const bf16x8*)&Qb[qoff + quad * 8];
        bf16x8 q1 = *(const bf16x8*)&Qb[qoff + 32 + quad * 8];
        qu0[c] = addbias(q0, &ub[h * 64 + quad * 8]);
        qu1[c] = addbias(q1, &ub[h * 64 + 32 + quad * 8]);
        qv0[c] = addbias(q0, &vb[h * 64 + quad * 8]);
        qv1[c] = addbias(q1, &vb[h * 64 + 32 + quad * 8]);
    }

    floatx4 O[2][4];
#pragma unroll
    for (int c = 0; c < 2; ++c)
#pragma unroll
        for (int dt = 0; dt < 4; ++dt) O[c][dt] = (floatx4){0.f, 0.f, 0.f, 0.f};
    float m_run[2] = {-3.0e38f, -3.0e38f}, l_run[2] = {0.f, 0.f};

    float* gw = (float*)&WaveBuf[w][0];
    u16*  pw  = (u16*)&WaveBuf[w][0];

    const int str = tid >> 3, stg = tid & 7;
    ushort8v kq[2], vq[2], pq[6];

#define LOAD_CHUNK(S0)                                                            \
    {                                                                             \
        _Pragma("unroll")                                                         \
        for (int it = 0; it < 2; ++it) {                                          \
            int r = str + it * 32;                                                \
            kq[it] = *(const ushort8v*)&Kb[(bh + (S0) + r) * 64 + stg * 8];       \
            vq[it] = *(const ushort8v*)&Vtg[(bhd + r) * 1024 + (S0) + stg * 8];   \
        }                                                                         \
        const int lb0 = 896 - t0 + (S0);                                          \
        _Pragma("unroll")                                                         \
        for (int it = 0; it < 6; ++it) {                                          \
            int r = str + it * 32;                                                \
            size_t l = (size_t)(lb0 + r);                                         \
            pq[it] = *(const ushort8v*)&P[((((size_t)h << 11) + l) << 6) + stg * 8]; \
        }                                                                         \
    }

    LOAD_CHUNK(0)

    for (int s0 = 0; s0 < 1024; s0 += 64) {
        __syncthreads();
#pragma unroll
        for (int it = 0; it < 2; ++it) {
            int r = str + it * 32;
            *(ushort8v*)&Klds[r * 72 + stg * 8] = kq[it];
            *(ushort8v*)&Vtlds[r * 72 + stg * 8] = vq[it];
        }
#pragma unroll
        for (int it = 0; it < 6; ++it) {
            int r = str + it * 32;
            *(ushort8v*)&Pb[r * 64 + ((stg ^ (r & 7)) << 3)] = pq[it];
        }
        __syncthreads();
        if (s0 + 64 < 1024) LOAD_CHUNK(s0 + 64)

        bf16x8 vf0[4], vf1[4];
#pragma unroll
        for (int dt = 0; dt < 4; ++dt) {
            int vr = dt * 16 + ln;
            vf0[dt] = *(bf16x8*)&Vtlds[vr * 72 + quad * 8];
            vf1[dt] = *(bf16x8*)&Vtlds[vr * 72 + 32 + quad * 8];
        }

#pragma unroll
        for (int c = 0; c < 2; ++c) {
            const u64 bits = Mp[mprow[c] + (s0 >> 6)];
            const int rb0 = 112 - 64 * c - 16 * w;
#pragma unroll
            for (int jt = 0; jt < 5; ++jt) {
                int rb = rb0 + jt * 16 + ln;
                bf16x8 a0 = *(bf16x8*)&Pb[rb * 64 + ((quad ^ (rb & 7)) << 3)];
                bf16x8 a1 = *(bf16x8*)&Pb[rb * 64 + (((4 + quad) ^ (rb & 7)) << 3)];
                floatx4 g = {0.f, 0.f, 0.f, 0.f};
                g = MFMA16(a0, qv0[c], g);
                g = MFMA16(a1, qv1[c], g);
                *(floatx4*)&gw[ln * 80 + jt * 16 + quad * 4] = g;
            }
            floatx4 cac[4];
#pragma unroll
            for (int st = 0; st < 4; ++st) {
                int kr = st * 16 + ln;
                bf16x8 a0 = *(bf16x8*)&Klds[kr * 72 + quad * 8];
                bf16x8 a1 = *(bf16x8*)&Klds[kr * 72 + 32 + quad * 8];
                floatx4 cc = {0.f, 0.f, 0.f, 0.f};
                cc = MFMA16(a0, qu0[c], cc);
                cc = MFMA16(a1, qu1[c], cc);
                cac[st] = cc;
            }
            float sc[4][4];
            float cmax = -3.0e38f;
#pragma unroll
            for (int st = 0; st < 4; ++st) {
                int j0 = st * 16 + quad * 4 + 15 - ln;
#pragma unroll
                for (int r = 0; r < 4; ++r) {
                    float v = (cac[st][r] + gw[ln * 80 + j0 + r]) * 0.125f;
                    int ss = st * 16 + quad * 4 + r;
                    v = ((bits >> ss) & 1ull) ? v : -1.0e30f;
                    sc[st][r] = v;
                    cmax = fmaxf(cmax, v);
                }
            }
            cmax = fmaxf(cmax, __shfl_xor(cmax, 16));
            cmax = fmaxf(cmax, __shfl_xor(cmax, 32));
            float m_new = fmaxf(m_run[c], cmax);
            float alpha = __expf(m_run[c] - m_new);
            float psum = 0.f;
#pragma unroll
            for (int st = 0; st < 4; ++st) {
                float p0 = __expf(sc[st][0] - m_new);
                float p1 = __expf(sc[st][1] - m_new);
                float p2 = __expf(sc[st][2] - m_new);
                float p3 = __expf(sc[st][3] - m_new);
                psum += (p0 + p1) + (p2 + p3);
                ushort4 pk;
                pk.x = f2b(p0); pk.y = f2b(p1); pk.z = f2b(p2); pk.w = f2b(p3);
                *(ushort4*)&pw[ln * 72 + st * 16 + quad * 4] = pk;
            }
            psum += __shfl_xor(psum, 16);
            psum += __shfl_xor(psum, 32);
            l_run[c] = l_run[c] * alpha + psum;
            m_run[c] = m_new;
            float a0s = __shfl(alpha, quad * 4 + 0);
            float a1s = __shfl(alpha, quad * 4 + 1);
            float a2s = __shfl(alpha, quad * 4 + 2);
            float a3s = __shfl(alpha, quad * 4 + 3);
#pragma unroll
            for (int dt = 0; dt < 4; ++dt) {
                O[c][dt][0] *= a0s; O[c][dt][1] *= a1s;
                O[c][dt][2] *= a2s; O[c][dt][3] *= a3s;
            }
            bf16x8 pa0 = *(bf16x8*)&pw[ln * 72 + quad * 8];
            bf16x8 pa1 = *(bf16x8*)&pw[ln * 72 + 32 + quad * 8];
#pragma unroll
            for (int dt = 0; dt < 4; ++dt) {
                O[c][dt] = MFMA16(pa0, vf0[dt], O[c][dt]);
                O[c][dt] = MFMA16(pa1, vf1[dt], O[c][dt]);
            }
        }
    }
#pragma unroll
    for (int c = 0; c < 2; ++c) {
        float li[4];
#pragma unroll
        for (int r = 0; r < 4; ++r) li[r] = 1.0f / __shfl(l_run[c], quad * 4 + r);
#pragma unroll
        for (int r = 0; r < 4; ++r) {
            size_t zo = ((size_t)b * 1024 + t0 + 64 * c + 16 * w + quad * 4 + r) * 512
                      + h * 64 + ln;
            Z[zo + 0]  = f2b(O[c][0][r] * li[r]);
            Z[zo + 16] = f2b(O[c][1][r] * li[r]);
            Z[zo + 32] = f2b(O[c][2][r] * li[r]);
            Z[zo + 48] = f2b(O[c][3][r] * li[r]);
        }
    }
}

// ---------------------------------------------------------------- out MFMA
__global__ __launch_bounds__(256, 2) void out_mfma(
    const u16* __restrict__ Zb, const u16* __restrict__ WoT,
    float* __restrict__ out)
{
    __shared__ u16 Xl[128 * 40];
    __shared__ u16 Wl[128 * 40];
    const int tid = threadIdx.x;
    const int lane = tid & 63, w = tid >> 6;
    const int quad = lane >> 4, ln = lane & 15;
    const int wm = w & 1, wn = w >> 1;
    const int m0 = blockIdx.x * 128;
    const int n0 = blockIdx.y * 128;
    const int sr = tid >> 2, sg = tid & 3;

    floatx4 acc[4][4];
#pragma unroll
    for (int i = 0; i < 4; ++i)
#pragma unroll
        for (int j = 0; j < 4; ++j) acc[i][j] = (floatx4){0.f, 0.f, 0.f, 0.f};

    ushort8v xq[2], wq2[2];
#pragma unroll
    for (int it = 0; it < 2; ++it) {
        int r = sr + it * 64;
        xq[it]  = *(const ushort8v*)&Zb[(size_t)(m0 + r) * 512 + sg * 8];
        wq2[it] = *(const ushort8v*)&WoT[(size_t)(n0 + r) * 512 + sg * 8];
    }

    for (int kc = 0; kc < 512; kc += 32) {
        __syncthreads();
#pragma unroll
        for (int it = 0; it < 2; ++it) {
            int r = sr + it * 64;
            *(ushort8v*)&Xl[r * 40 + sg * 8] = xq[it];
            *(ushort8v*)&Wl[r * 40 + sg * 8] = wq2[it];
        }
        __syncthreads();
        if (kc + 32 < 512) {
#pragma unroll
            for (int it = 0; it < 2; ++it) {
                int r = sr + it * 64;
                xq[it]  = *(const ushort8v*)&Zb[(size_t)(m0 + r) * 512 + kc + 32 + sg * 8];
                wq2[it] = *(const ushort8v*)&WoT[(size_t)(n0 + r) * 512 + kc + 32 + sg * 8];
            }
        }
        bf16x8 am[4], an[4];
#pragma unroll
        for (int i = 0; i < 4; ++i)
            am[i] = *(bf16x8*)&Xl[(wm * 64 + i * 16 + ln) * 40 + quad * 8];
#pragma unroll
        for (int j = 0; j < 4; ++j)
            an[j] = *(bf16x8*)&Wl[(wn * 64 + j * 16 + ln) * 40 + quad * 8];
#pragma unroll
        for (int i = 0; i < 4; ++i)
#pragma unroll
            for (int j = 0; j < 4; ++j)
                acc[i][j] = MFMA16(an[j], am[i], acc[i][j]);
    }
#pragma unroll
    for (int i = 0; i < 4; ++i) {
        int m = m0 + wm * 64 + i * 16 + ln;
#pragma unroll
        for (int j = 0; j < 4; ++j) {
            int n = n0 + wn * 64 + j * 16 + quad * 4;
            float4 s;
            s.x = acc[i][j][0]; s.y = acc[i][j][1];
            s.z = acc[i][j][2]; s.w = acc[i][j][3];
            *(float4*)&out[(size_t)m * 512 + n] = s;
        }
    }
}

// ---------------------------------------------------------------- launch
extern "C" void kernel_launch(void* const* d_in, const int* in_sizes, int n_in,
                              void* d_out, int out_size, void* d_ws, size_t ws_size,
                              hipStream_t stream) {
    const float* xs   = (const float*)d_in[0];
    const int*   mask = (const int*)d_in[1];
    const float* Wq   = (const float*)d_in[2];
    const float* Wk   = (const float*)d_in[3];
    const float* Wv   = (const float*)d_in[4];
    const float* Wpos = (const float*)d_in[5];
    const float* Wout = (const float*)d_in[6];
    const float* ub   = (const float*)d_in[7];
    const float* vb   = (const float*)d_in[8];
    float* out = (float*)d_out;

    u16* Qb  = (u16*)d_ws;                   // 4194304
    u16* Kb  = Qb + 4194304;                 // 4194304
    u16* Vtg = Kb + 4194304;                 // 4194304
    u16* Pg  = Vtg + 4194304;                // 8*2048*64 = 1048576
    u16* XZ  = Pg + 1048576;                 // 4194304 (Xb, then reused as Z)
    u16* WT  = XZ + 4194304;                 // 5*262144 = 1310720
    u16* WqT = WT;
    u16* WkT = WT + 262144;
    u16* WvT = WT + 524288;
    u16* WoT = WT + 786432;
    u16* WposT = WT + 1048576;
    u16* Peb = WT + 1310720;                 // 2048*512 = 1048576
    u64* Mp  = (u64*)(Peb + 1048576);        // 131072 u64

    prep_kernel<<<4928, 256, 0, stream>>>(xs, XZ, Wq, Wk, Wv, Wout, Wpos, WT,
                                          mask, Mp, Peb);
    qkv_mfma<<<dim3(64, 13), 256, 0, stream>>>(XZ, WqT, WkT, WvT, Peb, WposT,
                                               Qb, Kb, Vtg, Pg);
    attn_mfma<<<512, 256, 0, stream>>>(Qb, Kb, Vtg, Pg, Mp, ub, vb, XZ);
    out_mfma<<<dim3(64, 4), 256, 0, stream>>>(XZ, WoT, out);
}